// Round 6
// baseline (286.339 us; speedup 1.0000x reference)
//
#include <hip/hip_runtime.h>

// StealNMSLoss for MI355X (gfx950).  Round 6: LDS-free register-rolling
// column walk with DPP wave-shifts; dir map repacked to byte-planes.
//
// Phase 1 (dir_kernel): per (b,pixel) compute 2-bit NMS direction for ALL 16
//   classes from labels; store as 4 byte-planes dirs8[g][b][h][w], byte =
//   dirs of classes 4g..4g+3 (2 bits each).
// Phase 2 (nms_sum_kernel): wave owns a 64-col strip x 32 rows x 4 classes.
//   Rolling 4-row exp register window per class; horizontal/diagonal taps via
//   DPP wave_shr/shl (VALU pipe, no LDS).  17 strips of 60 output cols tile
//   the interior exactly; loads span cols [60s, 60s+64) in [0,1024) -> no
//   column clamping anywhere.
//
// Math notes (bit-exact rounds 1-5):
//  - Sobel-of-Sobel on one-hot mask = exact integer stencils /64.
//  - dir via exact integer Farey-bracket tests (t1: 100|gyy|>33|gxx|,
//    t2: 1000|gyy|>1377|gxx|); ng = (gyy<0)^(gxy>0)^(gxx<0).
//  - Only interior [2,H-2)x[2,W-2) contributes; dirs 1,3 share the
//    anti-diagonal denominator.  Denominator add-grouping here is pair-wise
//    ((a+b)+(c+d)) vs reference's left fold: <=1 ulp on a 4-term positive
//    sum, irrelevant at 2% tolerance.
//
// Round 5 post-mortem: nms ~72us; LDS gather (5 divergent ds_read/px on the
// shared per-CU LDS pipe) under-delivered.  This round: zero LDS in phase 2.

#define Bn 4
#define Cn 16
#define Hn 512
#define Wn 1024

typedef unsigned long long u64;
typedef unsigned int u32;
typedef float f4u __attribute__((ext_vector_type(4), aligned(4)));
typedef int   i4u __attribute__((ext_vector_type(4), aligned(4)));

static __device__ __forceinline__ float fast_rcp(float x) {
#if __has_builtin(__builtin_amdgcn_rcpf)
  return __builtin_amdgcn_rcpf(x);
#else
  return 1.0f / x;
#endif
}

// value from lane-1 (toward lower lane); lane 0 keeps own value (masked out)
static __device__ __forceinline__ float lane_up1(float x) {
#if __has_builtin(__builtin_amdgcn_update_dpp)
  return __int_as_float(__builtin_amdgcn_update_dpp(
      __float_as_int(x), __float_as_int(x), 0x138, 0xF, 0xF, false)); // WAVE_SHR:1
#else
  return __shfl_up(x, 1);
#endif
}
// value from lane+1; lane 63 keeps own value (masked out)
static __device__ __forceinline__ float lane_dn1(float x) {
#if __has_builtin(__builtin_amdgcn_update_dpp)
  return __int_as_float(__builtin_amdgcn_update_dpp(
      __float_as_int(x), __float_as_int(x), 0x130, 0xF, 0xF, false)); // WAVE_SHL:1
#else
  return __shfl_down(x, 1);
#endif
}

// ======================= Phase 1: direction map =======================
// Tile 128w x 8h, 256 threads = 32 tcols x 8 rows; thread owns 4 adjacent
// pixels in one row.  SWAR over 8 pixel-byte-lanes per u64.

#define P1TW 128
#define P1TH 8
#define P1LW 132
#define P1LH 12

__global__ __launch_bounds__(256)
void dir_kernel(const int* __restrict__ labels, u32* __restrict__ dirs8w)
{
  __shared__ unsigned char labt[P1LH][P1LW];

  const int w0 = blockIdx.x * P1TW;
  const int h0 = blockIdx.y * P1TH;
  const int b  = blockIdx.z;
  const int tid = threadIdx.x;

  const int* lbase = labels + (size_t)b * (Hn*Wn);
  const bool interior = (h0 >= 2) && (h0 + P1TH + 2 <= Hn) &&
                        (w0 >= 2) && (w0 + P1TW + 2 <= Wn);
  if (interior) {
    const int* lb = lbase + (size_t)(h0-2)*Wn + (w0-2);
    for (int i = tid; i < P1LH*33; i += 256) {
      int row = i / 33, c4 = (i - row*33) * 4;
      i4u L = *(const i4u*)(lb + row*Wn + c4);
      *(u32*)&labt[row][c4] =
          (u32)L.x | ((u32)L.y << 8) | ((u32)L.z << 16) | ((u32)L.w << 24);
    }
  } else {
    for (int i = tid; i < P1LH*33; i += 256) {
      int row = i / 33, c4 = (i - row*33) * 4;
      int gh = min(max(h0-2+row, 0), Hn-1);
      const int* lr = lbase + gh*Wn;
      u32 v = 0;
      #pragma unroll
      for (int k = 0; k < 4; ++k) {
        int gw = min(max(w0-2+c4+k, 0), Wn-1);
        v |= (u32)(lr[gw] & 0xff) << (8*k);
      }
      *(u32*)&labt[row][c4] = v;
    }
  }
  __syncthreads();

  const int tcol = tid & 31;
  const int trow = tid >> 5;

  u64 W[5];
  #pragma unroll
  for (int r = 0; r < 5; ++r) {
    const u32* lp = (const u32*)&labt[trow + r][0];
    u64 lo = lp[tcol];
    u64 hi = lp[tcol + 1];
    W[r] = lo | (hi << 32);
  }

  u32 pack[4] = {0u, 0u, 0u, 0u};   // pack[k]: px k, 2 bits per class

  #pragma unroll 1
  for (int c = 0; c < 16; ++c) {
    const u64 crep = 0x0101010101010101ULL * (u32)c;
    u64 m[5];
    #pragma unroll
    for (int r = 0; r < 5; ++r) {
      u64 x = W[r] ^ crep;
      m[r] = ((0x8080808080808080ULL - x) & 0x8080808080808080ULL) >> 7;
    }
    u64 t  = m[1] + m[3];
    u64 VA = m[0] + m[4] + (t << 2) + (m[2] << 2) + (m[2] << 1);
    u64 VB = ((m[3] << 1) + m[4] + 0x0303030303030303ULL)
             - (m[0] + (m[1] << 1));
    u64 VC = (m[0] + m[4] + 0x0202020202020202ULL) - (m[2] << 1);
    u64 gxxp = (VA + (VA >> 32) + 0x4040404040404040ULL) - ((VA >> 16) << 1);
    u64 q1   = (VC >> 8) + (VC >> 24);
    u64 w16  = VC >> 16;
    u64 gyyp = (VC + (VC >> 32)) + (q1 << 2) + (w16 << 2) + (w16 << 1);
    u64 gxyp = (((VB >> 24) << 1) + (VB >> 32) + 0x2020202020202020ULL)
             - (VB + ((VB >> 8) << 1));

    u32 gxxl = (u32)gxxp, gyyl = (u32)gyyp, gxyl = (u32)gxyp;
    #pragma unroll
    for (int k = 0; k < 4; ++k) {
      int gxx = (int)((gxxl >> (8*k)) & 0xffu) - 64;   // [-32,32]
      int gyy = (int)((gyyl >> (8*k)) & 0xffu) - 32;   // [-32,32]
      int gxyb = (int)((gxyl >> (8*k)) & 0xffu);       // >32 <=> gxy>0
      int ax = gxx < 0 ? -gxx : gxx;
      int ay = gyy < 0 ? -gyy : gyy;
      int t1 = (__mul24(ay, 100)  > __mul24(ax, 33))   ? 1 : 0;
      int t2 = (__mul24(ay, 1000) > __mul24(ax, 1377)) ? 1 : 0;
      int rb = t1 + t2;
      bool ng = ((gyy < 0) != (gxyb > 32)) != (gxx < 0);
      int dir = ng ? ((rb == 2) ? 3 : 0) : rb;
      pack[k] |= (u32)dir << (2*c);
    }
  }

  // scatter into 4 byte-planes: plane g byte = classes 4g..4g+3 of a pixel
  const int gh = h0 + trow;
  const size_t base = (size_t)gh*Wn + (w0 + 4*tcol);   // divisible by 4
  #pragma unroll
  for (int g = 0; g < 4; ++g) {
    u32 v =  ((pack[0] >> (8*g)) & 0xffu)
          | (((pack[1] >> (8*g)) & 0xffu) << 8)
          | (((pack[2] >> (8*g)) & 0xffu) << 16)
          | (((pack[3] >> (8*g)) & 0xffu) << 24);
    dirs8w[(((size_t)(g*Bn + b))*(Hn*Wn) + base) >> 2] = v;
  }
}

// ======================= Phase 2: exp / denom sum =======================
// grid (17, 4, 16), block 256 = 4 waves; wave wq handles chunk 4*by+wq.
// Wave: strip s (cols [60s,60s+64), outputs lanes 2..61), 32 rows, classes
// 4g..4g+3 of batch b.

__global__ __launch_bounds__(256)
void nms_sum_kernel(const float* __restrict__ pred,
                    const unsigned char* __restrict__ dirs8,
                    float* __restrict__ slots)
{
  const int lane = threadIdx.x & 63;
  const int wq   = threadIdx.x >> 6;
  const int s    = blockIdx.x;            // 0..16
  const int chunk = blockIdx.y * 4 + wq;  // 0..15
  const int zg   = blockIdx.z;            // 0..15
  const int b    = zg & 3;
  const int g    = zg >> 2;

  const int col = 60*s + lane;            // in [0,1024), no clamping needed
  const int r0  = 32*chunk;

  const float* pl[4];
  #pragma unroll
  for (int k = 0; k < 4; ++k)
    pl[k] = pred + (size_t)(b*Cn + 4*g + k)*(size_t)(Hn*Wn) + col;
  const unsigned char* dp = dirs8 + (size_t)(g*Bn + b)*(size_t)(Hn*Wn) + col;

  const float wvf = (lane >= 2 && lane < 62) ? 1.f : 0.f;

  // rolling window w[class][slot], slot = row & 3; prefill rows r0-2..r0
  float w[4][4];
  {
    const int rm2 = max(r0-2, 0), rm1 = max(r0-1, 0);
    #pragma unroll
    for (int k = 0; k < 4; ++k) {
      w[k][2] = __expf(pl[k][(size_t)rm2*Wn]);   // slot (r0-2)&3 = 2
      w[k][3] = __expf(pl[k][(size_t)rm1*Wn]);   // slot 3
      w[k][0] = __expf(pl[k][(size_t)r0 *Wn]);   // slot 0
    }
  }

  float acc = 0.f;

  #pragma unroll 1
  for (int i8 = 0; i8 < 8; ++i8) {
    #pragma unroll
    for (int kk = 0; kk < 4; ++kk) {
      const int r  = r0 + i8*4 + kk;
      const int rp = min(r+1, Hn-1);
      const u32 db = dp[(size_t)r*Wn];                 // dir byte, 4 classes
      const float nmask = ((u32)(r-2) < (u32)(Hn-4)) ? wvf : 0.f;

      #pragma unroll
      for (int k = 0; k < 4; ++k) {
        float ne = __expf(pl[k][(size_t)rp*Wn]);
        w[k][(kk+1)&3] = ne;
        const float e0 = w[k][(kk+2)&3];   // row r-2
        const float e1 = w[k][(kk+3)&3];   // row r-1
        const float e2 = w[k][ kk     ];   // row r
        const float e3 = ne;               // row r+1

        // horizontal: (c-2 + c-1) + (c + c+1)
        float d  = lane_dn1(e2);           // e2 at c+1
        float u  = e2 + d;
        float H  = lane_up1(lane_up1(u)) + u;
        // vertical: ((r-2 + r-1) + r) + r+1  (reference add order)
        float V  = ((e0 + e1) + e2) + e3;
        // anti-diagonal: (e0(c+1) + e1(c)) + (e2(c-1) + e3(c-2))
        float p  = lane_dn1(e0);
        float t  = e2 + lane_up1(e3);
        float D  = (p + e1) + lane_up1(t);

        int dir = (int)((db >> (2*k)) & 3u);
        float den = (dir == 0) ? H : ((dir == 2) ? V : D);
        acc = fmaf(nmask * e2, fast_rcp(den), acc);
      }
    }
  }

  // per-wave reduce -> one atomic per wave into 256 slots
  #pragma unroll
  for (int off = 32; off > 0; off >>= 1)
    acc += __shfl_down(acc, off);
  if (lane == 0)
    atomicAdd(&slots[(zg << 4) | ((s + chunk) & 15)], acc);
}

__global__ __launch_bounds__(64)
void reduce_ws_kernel(const float* __restrict__ slots, float* __restrict__ out)
{
  const int l = threadIdx.x;
  float s = (slots[l] + slots[l + 64]) + (slots[l + 128] + slots[l + 192]);
  #pragma unroll
  for (int off = 32; off > 0; off >>= 1)
    s += __shfl_down(s, off);
  if (l == 0) *out = s;
}

extern "C" void kernel_launch(void* const* d_in, const int* in_sizes, int n_in,
                              void* d_out, int out_size, void* d_ws, size_t ws_size,
                              hipStream_t stream) {
  (void)in_sizes; (void)n_in; (void)ws_size; (void)out_size;
  const float* pred   = (const float*)d_in[0];
  const int*   labels = (const int*)d_in[1];
  float* out = (float*)d_out;

  // d_ws layout: [0, 8 MB) dir byte-planes (fully overwritten by phase 1
  // each call), then 256 float reduction slots.  Needs ws_size >= 8.4 MB.
  u32* dirs8w = (u32*)d_ws;
  const unsigned char* dirs8 = (const unsigned char*)d_ws;
  float* slots = (float*)((char*)d_ws + (size_t)4*Bn*Hn*Wn);

  hipMemsetAsync(slots, 0, 256 * sizeof(float), stream);

  dir_kernel<<<dim3(Wn/P1TW, Hn/P1TH, Bn), 256, 0, stream>>>(labels, dirs8w);
  nms_sum_kernel<<<dim3(17, 4, 16), 256, 0, stream>>>(pred, dirs8, slots);
  reduce_ws_kernel<<<1, 64, 0, stream>>>(slots, out);
}